// Round 2
// baseline (550.801 us; speedup 1.0000x reference)
//
#include <hip/hip_runtime.h>

#define BN_EPS 1e-5f
#define CAP 3072   // per-bucket edge capacity (mean 1805, +30 sigma; guarded)

using bf16x8 = __attribute__((ext_vector_type(8))) short;
using f32x4  = __attribute__((ext_vector_type(4))) float;

__device__ __forceinline__ unsigned int f2bf(float f) {   // RTNE fp32->bf16
    unsigned int u = __float_as_uint(f);
    u += 0x7fffu + ((u >> 16) & 1u);
    return u >> 16;
}
__device__ __forceinline__ float bflo(unsigned int u) { return __uint_as_float(u << 16); }
__device__ __forceinline__ float bfhi(unsigned int u) { return __uint_as_float(u & 0xffff0000u); }

// ===================== scatter edges into fixed buckets =====================
__global__ __launch_bounds__(256) void k_bscatter(const int* __restrict__ ei,
                                                  int* __restrict__ bcur,
                                                  unsigned int* __restrict__ ebuf,
                                                  int E, int NB) {
    __shared__ int h[768];
    __shared__ int wb[768];
    for (int i = threadIdx.x; i < 768; i += 256) h[i] = 0;
    __syncthreads();
    int base = blockIdx.x * 8192;
    int rk[32];
    #pragma unroll
    for (int it = 0; it < 32; ++it) {
        int e = base + it * 256 + threadIdx.x;
        rk[it] = (e < E) ? atomicAdd(&h[ei[E + e] >> 8], 1) : 0;
    }
    __syncthreads();
    for (int i = threadIdx.x; i < NB; i += 256) {
        int c = h[i];
        wb[i] = c ? atomicAdd(&bcur[i], c) : 0;
    }
    __syncthreads();
    #pragma unroll
    for (int it = 0; it < 32; ++it) {
        int e = base + it * 256 + threadIdx.x;
        if (e < E) {
            unsigned s = (unsigned)ei[e], d = (unsigned)ei[E + e];
            int bk = (int)(d >> 8);
            int pos = wb[bk] + rk[it];
            if (pos < (bk + 1) * CAP)              // overflow guard (never hit)
                ebuf[pos] = s | ((d & 255u) << 24);
        }
    }
}

// ================== per-bucket finalize: count+scan+place ===================
__global__ __launch_bounds__(256) void k_bfinal(const unsigned int* __restrict__ ebuf,
                                                const int* __restrict__ bcur,
                                                int* __restrict__ csr,
                                                int* __restrict__ rs,
                                                int* __restrict__ re,
                                                float* __restrict__ dinv, int N) {
    __shared__ int cnt[256];
    __shared__ int scn[256];
    __shared__ int cur[256];
    const int t = threadIdx.x, b = blockIdx.x;
    const int beg = b * CAP;
    const int cntE = min(bcur[b] - beg, CAP);
    cnt[t] = 0;
    __syncthreads();
    for (int j = t; j < cntE; j += 256)
        atomicAdd(&cnt[ebuf[beg + j] >> 24], 1);
    __syncthreads();
    int v = cnt[t];
    scn[t] = v;
    __syncthreads();
    for (int off = 1; off < 256; off <<= 1) {
        int x = (t >= off) ? scn[t - off] : 0;
        __syncthreads();
        scn[t] += x;
        __syncthreads();
    }
    int excl = scn[t] - v;
    int node = b * 256 + t;
    if (node < N) {
        rs[node]   = beg + excl;
        re[node]   = beg + excl + v;
        dinv[node] = rsqrtf((float)(1 + v));   // +1 self-loop
    }
    cur[t] = beg + excl;
    __syncthreads();
    for (int j = t; j < cntE; j += 256) {
        unsigned e = ebuf[beg + j];
        int pos = atomicAdd(&cur[e >> 24], 1);
        csr[pos] = (int)(e & 0x00FFFFFFu);
    }
}

// ========= weight prep (+ folded init): 3 weights, bf16 B-frag order ========
__global__ __launch_bounds__(256) void k_prepW3(const float* __restrict__ W0,
                                                const float* __restrict__ W1,
                                                const float* __restrict__ W2,
                                                unsigned short* __restrict__ Wf,
                                                int* __restrict__ bcur,
                                                float* __restrict__ stats, int NB) {
    int t = blockIdx.x * 256 + threadIdx.x;   // 0..6143
    if (t < NB) bcur[t] = t * CAP;            // folded k_init
    if (t < 512) stats[t] = 0.f;              // zeroes stats0 + stats1
    int wid = t >> 11;                        // 0,1,2
    int f = t & 2047;
    const float* W = (wid == 0) ? W0 : (wid == 1) ? W1 : W2;
    int C = (wid == 2) ? 40 : 128;
    int lane = f & 63, frag = f >> 6;
    int kt = frag & 3, ct = frag >> 2;
    int r = lane & 15, q = lane >> 4;
    int col = ct * 16 + r;
    int kbase = kt * 32 + q * 8;
    unsigned int v[8];
    #pragma unroll
    for (int j = 0; j < 8; ++j)
        v[j] = (col < C) ? f2bf(W[(size_t)(kbase + j) * C + col]) : 0u;
    uint4 o;
    o.x = v[0] | (v[1] << 16);
    o.y = v[2] | (v[3] << 16);
    o.z = v[4] | (v[5] << 16);
    o.w = v[6] | (v[7] << 16);
    ((uint4*)Wf)[t] = o;
}

// ============================== MFMA GEMM ===================================
__device__ __forceinline__ float bn_apply(float v, int c, const float* stats,
                                          const float* g, const float* be, float invN) {
    float mean = stats[c] * invN;
    float var  = fmaf(-mean, mean, stats[128 + c] * invN);
    float sc   = g[c] * rsqrtf(var + BN_EPS);
    float r    = fmaf(v - mean, sc, be[c]);
    return fmaxf(r, 0.0f);
}

// H[N,OST]_bf16 = bf16( bn_relu(X)[N,128] @ W[:, :NOCT*16] )
template <int NOCT, int OST>
__global__ __launch_bounds__(256) void k_gemm_mfma(
        const void* __restrict__ X, int xf32, const unsigned short* __restrict__ Wf,
        unsigned short* __restrict__ H, int N,
        const float* __restrict__ stats, const float* __restrict__ g,
        const float* __restrict__ be) {
    __shared__ unsigned short aF[16 * 512];
    __shared__ unsigned short bF[NOCT * 4 * 512];
    const int tid = threadIdx.x;
    const int rowbase = blockIdx.x * 64;
    const float invN = 1.0f / (float)N;

    {   // stage B: NOCT col-tiles, lane-contiguous copy
        const uint4* src = (const uint4*)Wf;
        uint4* dst = (uint4*)bF;
        #pragma unroll
        for (int i = 0; i < NOCT; ++i) dst[tid + 256 * i] = src[tid + 256 * i];
    }
    // stage A: one frag-slot per task, BN+ReLU fused
    #pragma unroll
    for (int it = 0; it < 4; ++it) {
        int f = tid + 256 * it;
        int lane = f & 63, frag = f >> 6;
        int kt = frag & 3, rt = frag >> 2;
        int r = lane & 15, q = lane >> 4;
        int row = rowbase + rt * 16 + r;
        int kc = kt * 32 + q * 8;
        float vv[8];
        if (row < N) {
            if (xf32) {
                const float4* xp = (const float4*)((const float*)X + (size_t)row * 128 + kc);
                float4 p0 = xp[0], p1 = xp[1];
                vv[0] = p0.x; vv[1] = p0.y; vv[2] = p0.z; vv[3] = p0.w;
                vv[4] = p1.x; vv[5] = p1.y; vv[6] = p1.z; vv[7] = p1.w;
            } else {
                uint4 p = *((const uint4*)((const unsigned short*)X + (size_t)row * 128 + kc));
                vv[0] = bflo(p.x); vv[1] = bfhi(p.x);
                vv[2] = bflo(p.y); vv[3] = bfhi(p.y);
                vv[4] = bflo(p.z); vv[5] = bfhi(p.z);
                vv[6] = bflo(p.w); vv[7] = bfhi(p.w);
            }
            if (stats) {
                #pragma unroll
                for (int j = 0; j < 8; ++j)
                    vv[j] = bn_apply(vv[j], kc + j, stats, g, be, invN);
            }
        } else {
            #pragma unroll
            for (int j = 0; j < 8; ++j) vv[j] = 0.0f;
        }
        uint4 o;
        o.x = f2bf(vv[0]) | (f2bf(vv[1]) << 16);
        o.y = f2bf(vv[2]) | (f2bf(vv[3]) << 16);
        o.z = f2bf(vv[4]) | (f2bf(vv[5]) << 16);
        o.w = f2bf(vv[6]) | (f2bf(vv[7]) << 16);
        ((uint4*)aF)[f] = o;
    }
    __syncthreads();

    const int wave = tid >> 6, lane = tid & 63;
    f32x4 acc[NOCT];
    #pragma unroll
    for (int ct = 0; ct < NOCT; ++ct) acc[ct] = (f32x4){0.f, 0.f, 0.f, 0.f};

    #pragma unroll
    for (int kt = 0; kt < 4; ++kt) {
        bf16x8 a = ((const bf16x8*)aF)[(wave * 4 + kt) * 64 + lane];
        #pragma unroll
        for (int ct = 0; ct < NOCT; ++ct) {
            bf16x8 b = ((const bf16x8*)bF)[(ct * 4 + kt) * 64 + lane];
            acc[ct] = __builtin_amdgcn_mfma_f32_16x16x32_bf16(a, b, acc[ct], 0, 0, 0);
        }
    }

    const int q = lane >> 4, r = lane & 15;   // C/D: col=lane&15, row=q*4+reg
    #pragma unroll
    for (int ct = 0; ct < NOCT; ++ct) {
        #pragma unroll
        for (int i = 0; i < 4; ++i) {
            int row = rowbase + wave * 16 + q * 4 + i;
            if (row < N)
                H[(size_t)row * OST + ct * 16 + r] = (unsigned short)f2bf(acc[ct][i]);
        }
    }
}

// ========================= gather-based aggregate ===========================
// 16 lanes/node, uint4 (8ch) per lane; grid-stride over nodes with BN-stats
// fused: register partials s[8]/q[8] per thread (channels fixed per lane16),
// LDS reduce + rotated-address atomics at block end (replaces k_bnstats).
__global__ __launch_bounds__(256) void k_agg128(
        const unsigned short* __restrict__ H, const int* __restrict__ rs,
        const int* __restrict__ re, const int* __restrict__ csr,
        const float* __restrict__ dinv, const float* __restrict__ b,
        unsigned short* __restrict__ outb, float* __restrict__ stats, int N) {
    __shared__ float red[2][16][128];
    const int t = threadIdx.x;
    const int lane = t & 15, grp = t >> 4;
    float4 bb0 = ((const float4*)b)[lane * 2];
    float4 bb1 = ((const float4*)b)[lane * 2 + 1];
    float s[8], q[8];
    #pragma unroll
    for (int k = 0; k < 8; ++k) { s[k] = 0.f; q[k] = 0.f; }

    const int step = gridDim.x * 16;
    for (int node = blockIdx.x * 16 + grp; node < N; node += step) {
        float dd  = dinv[node];
        int   beg = rs[node];
        int   end = re[node];
        uint4 hp  = ((const uint4*)(H + (size_t)node * 128))[lane];
        float sl = dd * dd;
        float a0 = fmaf(bflo(hp.x), sl, bb0.x), a1 = fmaf(bfhi(hp.x), sl, bb0.y);
        float a2 = fmaf(bflo(hp.y), sl, bb0.z), a3 = fmaf(bfhi(hp.y), sl, bb0.w);
        float a4 = fmaf(bflo(hp.z), sl, bb1.x), a5 = fmaf(bfhi(hp.z), sl, bb1.y);
        float a6 = fmaf(bflo(hp.w), sl, bb1.z), a7 = fmaf(bfhi(hp.w), sl, bb1.w);
        int j = beg;
        for (; j + 2 <= end; j += 2) {
            int s0 = csr[j], s1 = csr[j + 1];
            float n0 = dinv[s0] * dd, n1 = dinv[s1] * dd;
            uint4 v0 = ((const uint4*)(H + (size_t)s0 * 128))[lane];
            uint4 v1 = ((const uint4*)(H + (size_t)s1 * 128))[lane];
            a0 = fmaf(bflo(v0.x), n0, fmaf(bflo(v1.x), n1, a0));
            a1 = fmaf(bfhi(v0.x), n0, fmaf(bfhi(v1.x), n1, a1));
            a2 = fmaf(bflo(v0.y), n0, fmaf(bflo(v1.y), n1, a2));
            a3 = fmaf(bfhi(v0.y), n0, fmaf(bfhi(v1.y), n1, a3));
            a4 = fmaf(bflo(v0.z), n0, fmaf(bflo(v1.z), n1, a4));
            a5 = fmaf(bfhi(v0.z), n0, fmaf(bfhi(v1.z), n1, a5));
            a6 = fmaf(bflo(v0.w), n0, fmaf(bflo(v1.w), n1, a6));
            a7 = fmaf(bfhi(v0.w), n0, fmaf(bfhi(v1.w), n1, a7));
        }
        if (j < end) {
            int s0 = csr[j];
            float n0 = dinv[s0] * dd;
            uint4 v0 = ((const uint4*)(H + (size_t)s0 * 128))[lane];
            a0 = fmaf(bflo(v0.x), n0, a0); a1 = fmaf(bfhi(v0.x), n0, a1);
            a2 = fmaf(bflo(v0.y), n0, a2); a3 = fmaf(bfhi(v0.y), n0, a3);
            a4 = fmaf(bflo(v0.z), n0, a4); a5 = fmaf(bfhi(v0.z), n0, a5);
            a6 = fmaf(bflo(v0.w), n0, a6); a7 = fmaf(bfhi(v0.w), n0, a7);
        }
        uint4 o;
        o.x = f2bf(a0) | (f2bf(a1) << 16);
        o.y = f2bf(a2) | (f2bf(a3) << 16);
        o.z = f2bf(a4) | (f2bf(a5) << 16);
        o.w = f2bf(a6) | (f2bf(a7) << 16);
        ((uint4*)(outb + (size_t)node * 128))[lane] = o;
        // BN-stat partials (fp32 pre-rounding values)
        s[0] += a0; q[0] = fmaf(a0, a0, q[0]);
        s[1] += a1; q[1] = fmaf(a1, a1, q[1]);
        s[2] += a2; q[2] = fmaf(a2, a2, q[2]);
        s[3] += a3; q[3] = fmaf(a3, a3, q[3]);
        s[4] += a4; q[4] = fmaf(a4, a4, q[4]);
        s[5] += a5; q[5] = fmaf(a5, a5, q[5]);
        s[6] += a6; q[6] = fmaf(a6, a6, q[6]);
        s[7] += a7; q[7] = fmaf(a7, a7, q[7]);
    }
    #pragma unroll
    for (int k = 0; k < 8; ++k) {
        red[0][grp][lane * 8 + k] = s[k];
        red[1][grp][lane * 8 + k] = q[k];
    }
    __syncthreads();
    // rotated-channel atomics: blocks target different addresses at any instant
    if (t < 128) {
        int c = (t + (blockIdx.x << 2)) & 127;
        float acc = 0.f;
        #pragma unroll
        for (int g = 0; g < 16; ++g) acc += red[0][g][c];
        unsafeAtomicAdd(&stats[c], acc);
    } else {
        int c = ((t - 128) + (blockIdx.x << 2)) & 127;
        float acc = 0.f;
        #pragma unroll
        for (int g = 0; g < 16; ++g) acc += red[1][g][c];
        unsafeAtomicAdd(&stats[128 + c], acc);
    }
}

// 40-ch final from compact stride-48 H (round-0 proven layout)
__global__ __launch_bounds__(256) void k_agg40(
        const unsigned short* __restrict__ H, const int* __restrict__ rs,
        const int* __restrict__ re, const int* __restrict__ csr,
        const float* __restrict__ dinv, const float* __restrict__ b,
        float* __restrict__ out, int N) {
    int lane = threadIdx.x & 15;
    int node = blockIdx.x * 16 + (threadIdx.x >> 4);
    if (node >= N || lane >= 10) return;
    float dd  = dinv[node];
    int   beg = rs[node];
    int   end = re[node];
    uint2 hp  = ((const uint2*)(H + (size_t)node * 48))[lane];
    float4 bb = ((const float4*)b)[lane];
    float  sl = dd * dd;
    float4 acc = make_float4(fmaf(bflo(hp.x), sl, bb.x), fmaf(bfhi(hp.x), sl, bb.y),
                             fmaf(bflo(hp.y), sl, bb.z), fmaf(bfhi(hp.y), sl, bb.w));
    int j = beg;
    for (; j + 2 <= end; j += 2) {
        int s0 = csr[j], s1 = csr[j + 1];
        float n0 = dinv[s0] * dd, n1 = dinv[s1] * dd;
        uint2 v0 = ((const uint2*)(H + (size_t)s0 * 48))[lane];
        uint2 v1 = ((const uint2*)(H + (size_t)s1 * 48))[lane];
        acc.x = fmaf(bflo(v0.x), n0, fmaf(bflo(v1.x), n1, acc.x));
        acc.y = fmaf(bfhi(v0.x), n0, fmaf(bfhi(v1.x), n1, acc.y));
        acc.z = fmaf(bflo(v0.y), n0, fmaf(bflo(v1.y), n1, acc.z));
        acc.w = fmaf(bfhi(v0.y), n0, fmaf(bfhi(v1.y), n1, acc.w));
    }
    if (j < end) {
        int s0 = csr[j];
        float n0 = dinv[s0] * dd;
        uint2 v0 = ((const uint2*)(H + (size_t)s0 * 48))[lane];
        acc.x = fmaf(bflo(v0.x), n0, acc.x);
        acc.y = fmaf(bfhi(v0.x), n0, acc.y);
        acc.z = fmaf(bflo(v0.y), n0, acc.z);
        acc.w = fmaf(bfhi(v0.y), n0, acc.w);
    }
    ((float4*)(out + (size_t)node * 40))[lane] = acc;
}

// ================================ launch ====================================
extern "C" void kernel_launch(void* const* d_in, const int* in_sizes, int n_in,
                              void* d_out, int out_size, void* d_ws, size_t ws_size,
                              hipStream_t stream) {
    const float* x   = (const float*)d_in[0];
    const int*   ei  = (const int*)d_in[1];      // int64 in ref -> int32 from harness
    const float* W0  = (const float*)d_in[2];
    const float* b0  = (const float*)d_in[3];
    const float* g0  = (const float*)d_in[4];
    const float* be0 = (const float*)d_in[5];
    const float* W1  = (const float*)d_in[6];
    const float* b1  = (const float*)d_in[7];
    const float* g1  = (const float*)d_in[8];
    const float* be1 = (const float*)d_in[9];
    const float* W2  = (const float*)d_in[10];
    const float* b2  = (const float*)d_in[11];
    float* out = (float*)d_out;

    const int N  = in_sizes[0] / 128;   // 170000
    const int E  = in_sizes[1] / 2;     // 1200000
    const int NB = (N + 255) >> 8;      // 665 buckets
    const int EB = (E + 8191) / 8192;   // 147 edge-chunk blocks

    // ws layout (4B units)
    float* ws   = (float*)d_ws;
    size_t Npad = ((size_t)N + 511) & ~(size_t)511;
    size_t BCAP = (size_t)NB * CAP;
    float* dinv = ws;
    int*   rs   = (int*)(ws + Npad);
    int*   re   = rs + Npad;
    int*   csr  = re + Npad;                            // BCAP
    unsigned int* ebuf = (unsigned int*)(csr + BCAP);   // BCAP
    int*   bcur = (int*)(ebuf + BCAP);                  // 1024
    float* stats0 = (float*)(bcur + 1024);              // 256
    float* stats1 = stats0 + 256;                       // 256
    unsigned short* Wf = (unsigned short*)(stats1 + 256); // 3*16384 ushort
    unsigned short* Hb = Wf + 3 * 16384;                // Npad*128 bf16
    unsigned short* Bb = Hb + Npad * 128;               // Npad*128 bf16

    // ---- prep (init folded) + CSR build: 3 dispatches ----
    k_prepW3  <<<24, 256, 0, stream>>>(W0, W1, W2, Wf, bcur, stats0, NB);
    k_bscatter<<<EB, 256, 0, stream>>>(ei, bcur, ebuf, E, NB);
    k_bfinal  <<<NB, 256, 0, stream>>>(ebuf, bcur, csr, rs, re, dinv, N);

    int gemm_grid = (N + 63) / 64;
    int agg_grid  = 2048;               // 8 blocks/CU resident, grid-stride
    int agg40_grid = (N + 15) / 16;

    // ---- layer 0 (agg fuses BN0 stats) ----
    k_gemm_mfma<8, 128><<<gemm_grid, 256, 0, stream>>>(x, 1, Wf, Hb, N,
                                                       nullptr, nullptr, nullptr);
    k_agg128<<<agg_grid, 256, 0, stream>>>(Hb, rs, re, csr, dinv, b0, Bb, stats0, N);

    // ---- layer 1 (BN0+ReLU fused into GEMM staging; agg fuses BN1 stats) ----
    k_gemm_mfma<8, 128><<<gemm_grid, 256, 0, stream>>>(Bb, 0, Wf + 16384, Hb, N,
                                                       stats0, g0, be0);
    k_agg128<<<agg_grid, 256, 0, stream>>>(Hb, rs, re, csr, dinv, b1, Bb, stats1, N);

    // ---- layer 2 (BN1+ReLU fused) -> compact 48-stride H -> 40-ch out ----
    k_gemm_mfma<3, 48><<<gemm_grid, 256, 0, stream>>>(Bb, 0, Wf + 2 * 16384, Hb, N,
                                                      stats1, g1, be1);
    k_agg40<<<agg40_grid, 256, 0, stream>>>(Hb, rs, re, csr, dinv, b2, out, N);
}

// Round 3
// 459.658 us; speedup vs baseline: 1.1983x; 1.1983x over previous
//
#include <hip/hip_runtime.h>

#define BN_EPS 1e-5f
#define CAP 3072   // per-bucket edge capacity (mean 1805, +30 sigma; guarded)

using bf16x8 = __attribute__((ext_vector_type(8))) short;
using f32x4  = __attribute__((ext_vector_type(4))) float;

__device__ __forceinline__ unsigned int f2bf(float f) {   // RTNE fp32->bf16
    unsigned int u = __float_as_uint(f);
    u += 0x7fffu + ((u >> 16) & 1u);
    return u >> 16;
}
__device__ __forceinline__ float bflo(unsigned int u) { return __uint_as_float(u << 16); }
__device__ __forceinline__ float bfhi(unsigned int u) { return __uint_as_float(u & 0xffff0000u); }

// ===================== scatter edges into fixed buckets =====================
__global__ __launch_bounds__(256) void k_bscatter(const int* __restrict__ ei,
                                                  int* __restrict__ bcur,
                                                  unsigned int* __restrict__ ebuf,
                                                  int E, int NB) {
    __shared__ int h[768];
    __shared__ int wb[768];
    for (int i = threadIdx.x; i < 768; i += 256) h[i] = 0;
    __syncthreads();
    int base = blockIdx.x * 8192;
    int rk[32];
    #pragma unroll
    for (int it = 0; it < 32; ++it) {
        int e = base + it * 256 + threadIdx.x;
        rk[it] = (e < E) ? atomicAdd(&h[ei[E + e] >> 8], 1) : 0;
    }
    __syncthreads();
    for (int i = threadIdx.x; i < NB; i += 256) {
        int c = h[i];
        wb[i] = c ? atomicAdd(&bcur[i], c) : 0;
    }
    __syncthreads();
    #pragma unroll
    for (int it = 0; it < 32; ++it) {
        int e = base + it * 256 + threadIdx.x;
        if (e < E) {
            unsigned s = (unsigned)ei[e], d = (unsigned)ei[E + e];
            int bk = (int)(d >> 8);
            int pos = wb[bk] + rk[it];
            if (pos < (bk + 1) * CAP)              // overflow guard (never hit)
                ebuf[pos] = s | ((d & 255u) << 24);
        }
    }
}

// ================== per-bucket finalize: count+scan+place ===================
__global__ __launch_bounds__(256) void k_bfinal(const unsigned int* __restrict__ ebuf,
                                                const int* __restrict__ bcur,
                                                int* __restrict__ csr,
                                                int* __restrict__ rs,
                                                int* __restrict__ re,
                                                float* __restrict__ dinv, int N) {
    __shared__ int cnt[256];
    __shared__ int scn[256];
    __shared__ int cur[256];
    const int t = threadIdx.x, b = blockIdx.x;
    const int beg = b * CAP;
    const int cntE = min(bcur[b] - beg, CAP);
    cnt[t] = 0;
    __syncthreads();
    for (int j = t; j < cntE; j += 256)
        atomicAdd(&cnt[ebuf[beg + j] >> 24], 1);
    __syncthreads();
    int v = cnt[t];
    scn[t] = v;
    __syncthreads();
    for (int off = 1; off < 256; off <<= 1) {
        int x = (t >= off) ? scn[t - off] : 0;
        __syncthreads();
        scn[t] += x;
        __syncthreads();
    }
    int excl = scn[t] - v;
    int node = b * 256 + t;
    if (node < N) {
        rs[node]   = beg + excl;
        re[node]   = beg + excl + v;
        dinv[node] = rsqrtf((float)(1 + v));   // +1 self-loop
    }
    cur[t] = beg + excl;
    __syncthreads();
    for (int j = t; j < cntE; j += 256) {
        unsigned e = ebuf[beg + j];
        int pos = atomicAdd(&cur[e >> 24], 1);
        csr[pos] = (int)(e & 0x00FFFFFFu);
    }
}

// ========= weight prep (+ folded init): 3 weights, bf16 B-frag order ========
__global__ __launch_bounds__(256) void k_prepW3(const float* __restrict__ W0,
                                                const float* __restrict__ W1,
                                                const float* __restrict__ W2,
                                                unsigned short* __restrict__ Wf,
                                                int* __restrict__ bcur,
                                                float* __restrict__ stats, int NB) {
    int t = blockIdx.x * 256 + threadIdx.x;   // 0..6143
    if (t < NB) bcur[t] = t * CAP;            // folded k_init
    if (t < 512) stats[t] = 0.f;              // zeroes stats0 + stats1
    int wid = t >> 11;                        // 0,1,2
    int f = t & 2047;
    const float* W = (wid == 0) ? W0 : (wid == 1) ? W1 : W2;
    int C = (wid == 2) ? 40 : 128;
    int lane = f & 63, frag = f >> 6;
    int kt = frag & 3, ct = frag >> 2;
    int r = lane & 15, q = lane >> 4;
    int col = ct * 16 + r;
    int kbase = kt * 32 + q * 8;
    unsigned int v[8];
    #pragma unroll
    for (int j = 0; j < 8; ++j)
        v[j] = (col < C) ? f2bf(W[(size_t)(kbase + j) * C + col]) : 0u;
    uint4 o;
    o.x = v[0] | (v[1] << 16);
    o.y = v[2] | (v[3] << 16);
    o.z = v[4] | (v[5] << 16);
    o.w = v[6] | (v[7] << 16);
    ((uint4*)Wf)[t] = o;
}

// ============================== MFMA GEMM ===================================
// BN scale/shift precomputed ONCE per block into LDS (sc,sh per channel);
// staging applies fmaf+max with a broadcast LDS read (16-lane groups share kc)
// instead of per-element rsqrtf + 4 VMEM loads.
template <int NOCT, int OST>
__global__ __launch_bounds__(256) void k_gemm_mfma(
        const void* __restrict__ X, int xf32, const unsigned short* __restrict__ Wf,
        unsigned short* __restrict__ H, int N,
        const float* __restrict__ stats, const float* __restrict__ g,
        const float* __restrict__ be) {
    __shared__ unsigned short aF[16 * 512];
    __shared__ unsigned short bF[NOCT * 4 * 512];
    __shared__ float2 bnss[128];
    const int tid = threadIdx.x;
    const int rowbase = blockIdx.x * 64;

    if (stats && tid < 128) {
        const float invN = 1.0f / (float)N;
        float mean = stats[tid] * invN;
        float var  = fmaf(-mean, mean, stats[128 + tid] * invN);
        float sc   = g[tid] * rsqrtf(var + BN_EPS);
        bnss[tid]  = make_float2(sc, fmaf(-mean, sc, be[tid]));
    }

    {   // stage B: NOCT col-tiles, lane-contiguous copy
        const uint4* src = (const uint4*)Wf;
        uint4* dst = (uint4*)bF;
        #pragma unroll
        for (int i = 0; i < NOCT; ++i) dst[tid + 256 * i] = src[tid + 256 * i];
    }
    __syncthreads();   // bnss ready before stage A consumes it

    // stage A: one frag-slot per task, BN+ReLU fused
    #pragma unroll
    for (int it = 0; it < 4; ++it) {
        int f = tid + 256 * it;
        int lane = f & 63, frag = f >> 6;
        int kt = frag & 3, rt = frag >> 2;
        int r = lane & 15, q = lane >> 4;
        int row = rowbase + rt * 16 + r;
        int kc = kt * 32 + q * 8;
        float vv[8];
        if (row < N) {
            if (xf32) {
                const float4* xp = (const float4*)((const float*)X + (size_t)row * 128 + kc);
                float4 p0 = xp[0], p1 = xp[1];
                vv[0] = p0.x; vv[1] = p0.y; vv[2] = p0.z; vv[3] = p0.w;
                vv[4] = p1.x; vv[5] = p1.y; vv[6] = p1.z; vv[7] = p1.w;
            } else {
                uint4 p = *((const uint4*)((const unsigned short*)X + (size_t)row * 128 + kc));
                vv[0] = bflo(p.x); vv[1] = bfhi(p.x);
                vv[2] = bflo(p.y); vv[3] = bfhi(p.y);
                vv[4] = bflo(p.z); vv[5] = bfhi(p.z);
                vv[6] = bflo(p.w); vv[7] = bfhi(p.w);
            }
            if (stats) {
                #pragma unroll
                for (int j = 0; j < 8; ++j) {
                    float2 ss = bnss[kc + j];
                    vv[j] = fmaxf(fmaf(vv[j], ss.x, ss.y), 0.0f);
                }
            }
        } else {
            #pragma unroll
            for (int j = 0; j < 8; ++j) vv[j] = 0.0f;
        }
        uint4 o;
        o.x = f2bf(vv[0]) | (f2bf(vv[1]) << 16);
        o.y = f2bf(vv[2]) | (f2bf(vv[3]) << 16);
        o.z = f2bf(vv[4]) | (f2bf(vv[5]) << 16);
        o.w = f2bf(vv[6]) | (f2bf(vv[7]) << 16);
        ((uint4*)aF)[f] = o;
    }
    __syncthreads();

    const int wave = tid >> 6, lane = tid & 63;
    f32x4 acc[NOCT];
    #pragma unroll
    for (int ct = 0; ct < NOCT; ++ct) acc[ct] = (f32x4){0.f, 0.f, 0.f, 0.f};

    #pragma unroll
    for (int kt = 0; kt < 4; ++kt) {
        bf16x8 a = ((const bf16x8*)aF)[(wave * 4 + kt) * 64 + lane];
        #pragma unroll
        for (int ct = 0; ct < NOCT; ++ct) {
            bf16x8 b = ((const bf16x8*)bF)[(ct * 4 + kt) * 64 + lane];
            acc[ct] = __builtin_amdgcn_mfma_f32_16x16x32_bf16(a, b, acc[ct], 0, 0, 0);
        }
    }

    const int q = lane >> 4, r = lane & 15;   // C/D: col=lane&15, row=q*4+reg
    #pragma unroll
    for (int ct = 0; ct < NOCT; ++ct) {
        #pragma unroll
        for (int i = 0; i < 4; ++i) {
            int row = rowbase + wave * 16 + q * 4 + i;
            if (row < N)
                H[(size_t)row * OST + ct * 16 + r] = (unsigned short)f2bf(acc[ct][i]);
        }
    }
}

// ========================= gather-based aggregate ===========================
// 16 lanes/node, uint4 (8ch) per lane. (round-0 proven form)
__global__ __launch_bounds__(256) void k_agg128(
        const unsigned short* __restrict__ H, const int* __restrict__ rs,
        const int* __restrict__ re, const int* __restrict__ csr,
        const float* __restrict__ dinv, const float* __restrict__ b,
        unsigned short* __restrict__ outb, int N) {
    int lane = threadIdx.x & 15;
    int node = blockIdx.x * 16 + (threadIdx.x >> 4);
    if (node >= N) return;
    float dd  = dinv[node];
    int   beg = rs[node];
    int   end = re[node];
    uint4 hp  = ((const uint4*)(H + (size_t)node * 128))[lane];
    float4 bb0 = ((const float4*)b)[lane * 2];
    float4 bb1 = ((const float4*)b)[lane * 2 + 1];
    float sl = dd * dd;
    float a0 = fmaf(bflo(hp.x), sl, bb0.x), a1 = fmaf(bfhi(hp.x), sl, bb0.y);
    float a2 = fmaf(bflo(hp.y), sl, bb0.z), a3 = fmaf(bfhi(hp.y), sl, bb0.w);
    float a4 = fmaf(bflo(hp.z), sl, bb1.x), a5 = fmaf(bfhi(hp.z), sl, bb1.y);
    float a6 = fmaf(bflo(hp.w), sl, bb1.z), a7 = fmaf(bfhi(hp.w), sl, bb1.w);
    int j = beg;
    for (; j + 2 <= end; j += 2) {
        int s0 = csr[j], s1 = csr[j + 1];
        float n0 = dinv[s0] * dd, n1 = dinv[s1] * dd;
        uint4 v0 = ((const uint4*)(H + (size_t)s0 * 128))[lane];
        uint4 v1 = ((const uint4*)(H + (size_t)s1 * 128))[lane];
        a0 = fmaf(bflo(v0.x), n0, fmaf(bflo(v1.x), n1, a0));
        a1 = fmaf(bfhi(v0.x), n0, fmaf(bfhi(v1.x), n1, a1));
        a2 = fmaf(bflo(v0.y), n0, fmaf(bflo(v1.y), n1, a2));
        a3 = fmaf(bfhi(v0.y), n0, fmaf(bfhi(v1.y), n1, a3));
        a4 = fmaf(bflo(v0.z), n0, fmaf(bflo(v1.z), n1, a4));
        a5 = fmaf(bfhi(v0.z), n0, fmaf(bfhi(v1.z), n1, a5));
        a6 = fmaf(bflo(v0.w), n0, fmaf(bflo(v1.w), n1, a6));
        a7 = fmaf(bfhi(v0.w), n0, fmaf(bfhi(v1.w), n1, a7));
    }
    if (j < end) {
        int s0 = csr[j];
        float n0 = dinv[s0] * dd;
        uint4 v0 = ((const uint4*)(H + (size_t)s0 * 128))[lane];
        a0 = fmaf(bflo(v0.x), n0, a0); a1 = fmaf(bfhi(v0.x), n0, a1);
        a2 = fmaf(bflo(v0.y), n0, a2); a3 = fmaf(bfhi(v0.y), n0, a3);
        a4 = fmaf(bflo(v0.z), n0, a4); a5 = fmaf(bfhi(v0.z), n0, a5);
        a6 = fmaf(bflo(v0.w), n0, a6); a7 = fmaf(bfhi(v0.w), n0, a7);
    }
    uint4 o;
    o.x = f2bf(a0) | (f2bf(a1) << 16);
    o.y = f2bf(a2) | (f2bf(a3) << 16);
    o.z = f2bf(a4) | (f2bf(a5) << 16);
    o.w = f2bf(a6) | (f2bf(a7) << 16);
    ((uint4*)(outb + (size_t)node * 128))[lane] = o;
}

// 40-ch final from compact stride-48 H
__global__ __launch_bounds__(256) void k_agg40(
        const unsigned short* __restrict__ H, const int* __restrict__ rs,
        const int* __restrict__ re, const int* __restrict__ csr,
        const float* __restrict__ dinv, const float* __restrict__ b,
        float* __restrict__ out, int N) {
    int lane = threadIdx.x & 15;
    int node = blockIdx.x * 16 + (threadIdx.x >> 4);
    if (node >= N || lane >= 10) return;
    float dd  = dinv[node];
    int   beg = rs[node];
    int   end = re[node];
    uint2 hp  = ((const uint2*)(H + (size_t)node * 48))[lane];
    float4 bb = ((const float4*)b)[lane];
    float  sl = dd * dd;
    float4 acc = make_float4(fmaf(bflo(hp.x), sl, bb.x), fmaf(bfhi(hp.x), sl, bb.y),
                             fmaf(bflo(hp.y), sl, bb.z), fmaf(bfhi(hp.y), sl, bb.w));
    int j = beg;
    for (; j + 2 <= end; j += 2) {
        int s0 = csr[j], s1 = csr[j + 1];
        float n0 = dinv[s0] * dd, n1 = dinv[s1] * dd;
        uint2 v0 = ((const uint2*)(H + (size_t)s0 * 48))[lane];
        uint2 v1 = ((const uint2*)(H + (size_t)s1 * 48))[lane];
        acc.x = fmaf(bflo(v0.x), n0, fmaf(bflo(v1.x), n1, acc.x));
        acc.y = fmaf(bfhi(v0.x), n0, fmaf(bfhi(v1.x), n1, acc.y));
        acc.z = fmaf(bflo(v0.y), n0, fmaf(bflo(v1.y), n1, acc.z));
        acc.w = fmaf(bfhi(v0.y), n0, fmaf(bfhi(v1.y), n1, acc.w));
    }
    if (j < end) {
        int s0 = csr[j];
        float n0 = dinv[s0] * dd;
        uint2 v0 = ((const uint2*)(H + (size_t)s0 * 48))[lane];
        acc.x = fmaf(bflo(v0.x), n0, acc.x);
        acc.y = fmaf(bfhi(v0.x), n0, acc.y);
        acc.z = fmaf(bflo(v0.y), n0, acc.z);
        acc.w = fmaf(bfhi(v0.y), n0, acc.w);
    }
    ((float4*)(out + (size_t)node * 40))[lane] = acc;
}

// =============================== BN stats ===================================
__global__ __launch_bounds__(256) void k_bnstats(
        const unsigned short* __restrict__ Bb, float* __restrict__ stats, int N) {
    __shared__ float red[2][16][128];
    const int t = threadIdx.x;
    const int lane16 = t & 15, grp = t >> 4;
    const int cbase = lane16 * 8;
    float s[8], q[8];
    #pragma unroll
    for (int k = 0; k < 8; ++k) { s[k] = 0.f; q[k] = 0.f; }

    const int step = gridDim.x * 16;
    for (int r = blockIdx.x * 16 + grp; r < N; r += 2 * step) {
        uint4 p0 = *((const uint4*)(Bb + (size_t)r * 128 + cbase));
        int r1 = r + step;
        if (r1 < N) {
            uint4 p1 = *((const uint4*)(Bb + (size_t)r1 * 128 + cbase));
            float v[8] = {bflo(p1.x), bfhi(p1.x), bflo(p1.y), bfhi(p1.y),
                          bflo(p1.z), bfhi(p1.z), bflo(p1.w), bfhi(p1.w)};
            #pragma unroll
            for (int k = 0; k < 8; ++k) { s[k] += v[k]; q[k] = fmaf(v[k], v[k], q[k]); }
        }
        float u[8] = {bflo(p0.x), bfhi(p0.x), bflo(p0.y), bfhi(p0.y),
                      bflo(p0.z), bfhi(p0.z), bflo(p0.w), bfhi(p0.w)};
        #pragma unroll
        for (int k = 0; k < 8; ++k) { s[k] += u[k]; q[k] = fmaf(u[k], u[k], q[k]); }
    }
    #pragma unroll
    for (int k = 0; k < 8; ++k) {
        red[0][grp][cbase + k] = s[k];
        red[1][grp][cbase + k] = q[k];
    }
    __syncthreads();
    if (t < 128) {
        float acc = 0.f;
        #pragma unroll
        for (int g = 0; g < 16; ++g) acc += red[0][g][t];
        unsafeAtomicAdd(&stats[t], acc);
    } else {
        int c = t - 128;
        float acc = 0.f;
        #pragma unroll
        for (int g = 0; g < 16; ++g) acc += red[1][g][c];
        unsafeAtomicAdd(&stats[128 + c], acc);
    }
}

// ================================ launch ====================================
extern "C" void kernel_launch(void* const* d_in, const int* in_sizes, int n_in,
                              void* d_out, int out_size, void* d_ws, size_t ws_size,
                              hipStream_t stream) {
    const float* x   = (const float*)d_in[0];
    const int*   ei  = (const int*)d_in[1];      // int64 in ref -> int32 from harness
    const float* W0  = (const float*)d_in[2];
    const float* b0  = (const float*)d_in[3];
    const float* g0  = (const float*)d_in[4];
    const float* be0 = (const float*)d_in[5];
    const float* W1  = (const float*)d_in[6];
    const float* b1  = (const float*)d_in[7];
    const float* g1  = (const float*)d_in[8];
    const float* be1 = (const float*)d_in[9];
    const float* W2  = (const float*)d_in[10];
    const float* b2  = (const float*)d_in[11];
    float* out = (float*)d_out;

    const int N  = in_sizes[0] / 128;   // 170000
    const int E  = in_sizes[1] / 2;     // 1200000
    const int NB = (N + 255) >> 8;      // 665 buckets
    const int EB = (E + 8191) / 8192;   // 147 edge-chunk blocks

    // ws layout (4B units)
    float* ws   = (float*)d_ws;
    size_t Npad = ((size_t)N + 511) & ~(size_t)511;
    size_t BCAP = (size_t)NB * CAP;
    float* dinv = ws;
    int*   rs   = (int*)(ws + Npad);
    int*   re   = rs + Npad;
    int*   csr  = re + Npad;                            // BCAP
    unsigned int* ebuf = (unsigned int*)(csr + BCAP);   // BCAP
    int*   bcur = (int*)(ebuf + BCAP);                  // 1024
    float* stats0 = (float*)(bcur + 1024);              // 256
    float* stats1 = stats0 + 256;                       // 256
    unsigned short* Wf = (unsigned short*)(stats1 + 256); // 3*16384 ushort
    unsigned short* Hb = Wf + 3 * 16384;                // Npad*128 bf16
    unsigned short* Bb = Hb + Npad * 128;               // Npad*128 bf16

    // ---- prep (init folded) + CSR build: 3 dispatches ----
    k_prepW3  <<<24, 256, 0, stream>>>(W0, W1, W2, Wf, bcur, stats0, NB);
    k_bscatter<<<EB, 256, 0, stream>>>(ei, bcur, ebuf, E, NB);
    k_bfinal  <<<NB, 256, 0, stream>>>(ebuf, bcur, csr, rs, re, dinv, N);

    int gemm_grid = (N + 63) / 64;
    int agg_grid  = (N + 15) / 16;

    // ---- layer 0 ----
    k_gemm_mfma<8, 128><<<gemm_grid, 256, 0, stream>>>(x, 1, Wf, Hb, N,
                                                       nullptr, nullptr, nullptr);
    k_agg128<<<agg_grid, 256, 0, stream>>>(Hb, rs, re, csr, dinv, b0, Bb, N);
    k_bnstats<<<512, 256, 0, stream>>>(Bb, stats0, N);

    // ---- layer 1 (BN0+ReLU fused into GEMM staging, LDS-precomputed) ----
    k_gemm_mfma<8, 128><<<gemm_grid, 256, 0, stream>>>(Bb, 0, Wf + 16384, Hb, N,
                                                       stats0, g0, be0);
    k_agg128<<<agg_grid, 256, 0, stream>>>(Hb, rs, re, csr, dinv, b1, Bb, N);
    k_bnstats<<<512, 256, 0, stream>>>(Bb, stats1, N);

    // ---- layer 2 (BN1+ReLU fused) -> compact 48-stride H -> 40-ch out ----
    k_gemm_mfma<3, 48><<<gemm_grid, 256, 0, stream>>>(Bb, 0, Wf + 2 * 16384, Hb, N,
                                                      stats1, g1, be1);
    k_agg40<<<agg_grid, 256, 0, stream>>>(Hb, rs, re, csr, dinv, b2, out, N);
}

// Round 4
// 455.435 us; speedup vs baseline: 1.2094x; 1.0093x over previous
//
#include <hip/hip_runtime.h>

#define BN_EPS 1e-5f
#define CAP 3072   // per-bucket edge capacity (mean 1805, +30 sigma; guarded)

using bf16x8 = __attribute__((ext_vector_type(8))) short;
using f32x4  = __attribute__((ext_vector_type(4))) float;

__device__ __forceinline__ unsigned int f2bf(float f) {   // RTNE fp32->bf16
    unsigned int u = __float_as_uint(f);
    u += 0x7fffu + ((u >> 16) & 1u);
    return u >> 16;
}
// packed RTNE fp32x2 -> bf16x2 (bit-identical to f2bf pair)
__device__ __forceinline__ unsigned int f2bf2(float lo, float hi) {
    unsigned int r;
    asm("v_cvt_pk_bf16_f32 %0, %1, %2" : "=v"(r) : "v"(lo), "v"(hi));
    return r;
}
__device__ __forceinline__ float bflo(unsigned int u) { return __uint_as_float(u << 16); }
__device__ __forceinline__ float bfhi(unsigned int u) { return __uint_as_float(u & 0xffff0000u); }

// ===================== scatter edges into fixed buckets =====================
__global__ __launch_bounds__(256) void k_bscatter(const int* __restrict__ ei,
                                                  int* __restrict__ bcur,
                                                  unsigned int* __restrict__ ebuf,
                                                  int E, int NB) {
    __shared__ int h[768];
    __shared__ int wb[768];
    for (int i = threadIdx.x; i < 768; i += 256) h[i] = 0;
    __syncthreads();
    int base = blockIdx.x * 8192;
    int rk[32];
    #pragma unroll
    for (int it = 0; it < 32; ++it) {
        int e = base + it * 256 + threadIdx.x;
        rk[it] = (e < E) ? atomicAdd(&h[ei[E + e] >> 8], 1) : 0;
    }
    __syncthreads();
    for (int i = threadIdx.x; i < NB; i += 256) {
        int c = h[i];
        wb[i] = c ? atomicAdd(&bcur[i], c) : 0;
    }
    __syncthreads();
    #pragma unroll
    for (int it = 0; it < 32; ++it) {
        int e = base + it * 256 + threadIdx.x;
        if (e < E) {
            unsigned s = (unsigned)ei[e], d = (unsigned)ei[E + e];
            int bk = (int)(d >> 8);
            int pos = wb[bk] + rk[it];
            if (pos < (bk + 1) * CAP)              // overflow guard (never hit)
                ebuf[pos] = s | ((d & 255u) << 24);
        }
    }
}

// ================== per-bucket finalize: count+scan+place ===================
__global__ __launch_bounds__(256) void k_bfinal(const unsigned int* __restrict__ ebuf,
                                                const int* __restrict__ bcur,
                                                int* __restrict__ csr,
                                                int* __restrict__ rs,
                                                int* __restrict__ re,
                                                float* __restrict__ dinv, int N) {
    __shared__ int cnt[256];
    __shared__ int scn[256];
    __shared__ int cur[256];
    const int t = threadIdx.x, b = blockIdx.x;
    const int beg = b * CAP;
    const int cntE = min(bcur[b] - beg, CAP);
    cnt[t] = 0;
    __syncthreads();
    for (int j = t; j < cntE; j += 256)
        atomicAdd(&cnt[ebuf[beg + j] >> 24], 1);
    __syncthreads();
    int v = cnt[t];
    scn[t] = v;
    __syncthreads();
    for (int off = 1; off < 256; off <<= 1) {
        int x = (t >= off) ? scn[t - off] : 0;
        __syncthreads();
        scn[t] += x;
        __syncthreads();
    }
    int excl = scn[t] - v;
    int node = b * 256 + t;
    if (node < N) {
        rs[node]   = beg + excl;
        re[node]   = beg + excl + v;
        dinv[node] = rsqrtf((float)(1 + v));   // +1 self-loop
    }
    cur[t] = beg + excl;
    __syncthreads();
    for (int j = t; j < cntE; j += 256) {
        unsigned e = ebuf[beg + j];
        int pos = atomicAdd(&cur[e >> 24], 1);
        csr[pos] = (int)(e & 0x00FFFFFFu);
    }
}

// ========= weight prep (+ folded init): 3 weights, bf16 B-frag order ========
__global__ __launch_bounds__(256) void k_prepW3(const float* __restrict__ W0,
                                                const float* __restrict__ W1,
                                                const float* __restrict__ W2,
                                                unsigned short* __restrict__ Wf,
                                                int* __restrict__ bcur,
                                                float* __restrict__ stats, int NB) {
    int t = blockIdx.x * 256 + threadIdx.x;   // 0..6143
    if (t < NB) bcur[t] = t * CAP;            // folded k_init
    if (t < 512) stats[t] = 0.f;              // zeroes stats0 + stats1
    int wid = t >> 11;                        // 0,1,2
    int f = t & 2047;
    const float* W = (wid == 0) ? W0 : (wid == 1) ? W1 : W2;
    int C = (wid == 2) ? 40 : 128;
    int lane = f & 63, frag = f >> 6;
    int kt = frag & 3, ct = frag >> 2;
    int r = lane & 15, q = lane >> 4;
    int col = ct * 16 + r;
    int kbase = kt * 32 + q * 8;
    unsigned int v[8];
    #pragma unroll
    for (int j = 0; j < 8; ++j)
        v[j] = (col < C) ? f2bf(W[(size_t)(kbase + j) * C + col]) : 0u;
    uint4 o;
    o.x = v[0] | (v[1] << 16);
    o.y = v[2] | (v[3] << 16);
    o.z = v[4] | (v[5] << 16);
    o.w = v[6] | (v[7] << 16);
    ((uint4*)Wf)[t] = o;
}

// ============================== MFMA GEMM ===================================
// No A-LDS: each wave loads its own 16x128 A-tile directly from global in
// MFMA fragment order (lane = row + 16q, k = kt*32 + q*8 -> coalesced uint4).
// BN scale/shift precomputed once per block into LDS; bf16 pack via cvt_pk.
template <int NOCT, int OST>
__global__ __launch_bounds__(256) void k_gemm_mfma(
        const void* __restrict__ X, int xf32, const unsigned short* __restrict__ Wf,
        unsigned short* __restrict__ H, int N,
        const float* __restrict__ stats, const float* __restrict__ g,
        const float* __restrict__ be) {
    __shared__ unsigned short bF[NOCT * 4 * 512];
    __shared__ float2 bnss[128];
    const int tid = threadIdx.x;
    const int rowbase = blockIdx.x * 64;

    if (stats && tid < 128) {
        const float invN = 1.0f / (float)N;
        float mean = stats[tid] * invN;
        float var  = fmaf(-mean, mean, stats[128 + tid] * invN);
        float sc   = g[tid] * rsqrtf(var + BN_EPS);
        bnss[tid]  = make_float2(sc, fmaf(-mean, sc, be[tid]));
    }
    {   // stage B: NOCT col-tiles, lane-contiguous copy
        const uint4* src = (const uint4*)Wf;
        uint4* dst = (uint4*)bF;
        #pragma unroll
        for (int i = 0; i < NOCT; ++i) dst[tid + 256 * i] = src[tid + 256 * i];
    }
    __syncthreads();   // bF + bnss ready

    const int wave = tid >> 6, lane = tid & 63;
    const int r = lane & 15, q = lane >> 4;
    const int row  = rowbase + wave * 16 + r;
    const int rowc = min(row, N - 1);          // clamp: OOB rows computed, not stored

    bf16x8 afr[4];
    #pragma unroll
    for (int kt = 0; kt < 4; ++kt) {
        const int kc = kt * 32 + q * 8;
        float vv[8];
        if (xf32) {
            const float4* xp = (const float4*)((const float*)X + (size_t)rowc * 128 + kc);
            float4 p0 = xp[0], p1 = xp[1];
            vv[0] = p0.x; vv[1] = p0.y; vv[2] = p0.z; vv[3] = p0.w;
            vv[4] = p1.x; vv[5] = p1.y; vv[6] = p1.z; vv[7] = p1.w;
        } else {
            uint4 p = *((const uint4*)((const unsigned short*)X + (size_t)rowc * 128 + kc));
            vv[0] = bflo(p.x); vv[1] = bfhi(p.x);
            vv[2] = bflo(p.y); vv[3] = bfhi(p.y);
            vv[4] = bflo(p.z); vv[5] = bfhi(p.z);
            vv[6] = bflo(p.w); vv[7] = bfhi(p.w);
        }
        if (stats) {
            #pragma unroll
            for (int j = 0; j < 8; ++j) {
                float2 ss = bnss[kc + j];
                vv[j] = fmaxf(fmaf(vv[j], ss.x, ss.y), 0.0f);
            }
        }
        union { unsigned int u[4]; bf16x8 v; } pk;
        pk.u[0] = f2bf2(vv[0], vv[1]);
        pk.u[1] = f2bf2(vv[2], vv[3]);
        pk.u[2] = f2bf2(vv[4], vv[5]);
        pk.u[3] = f2bf2(vv[6], vv[7]);
        afr[kt] = pk.v;
    }

    f32x4 acc[NOCT];
    #pragma unroll
    for (int ct = 0; ct < NOCT; ++ct) acc[ct] = (f32x4){0.f, 0.f, 0.f, 0.f};

    #pragma unroll
    for (int kt = 0; kt < 4; ++kt) {
        #pragma unroll
        for (int ct = 0; ct < NOCT; ++ct) {
            bf16x8 b = ((const bf16x8*)bF)[(ct * 4 + kt) * 64 + lane];
            acc[ct] = __builtin_amdgcn_mfma_f32_16x16x32_bf16(afr[kt], b, acc[ct], 0, 0, 0);
        }
    }

    // C/D: col = ct*16 + r, row = q*4 + i; pack row-pairs, split halves
    #pragma unroll
    for (int ct = 0; ct < NOCT; ++ct) {
        #pragma unroll
        for (int i = 0; i < 4; i += 2) {
            int row0 = rowbase + wave * 16 + q * 4 + i;
            unsigned int pk = f2bf2(acc[ct][i], acc[ct][i + 1]);
            if (row0 < N)
                H[(size_t)row0 * OST + ct * 16 + r] = (unsigned short)pk;
            if (row0 + 1 < N)
                H[(size_t)(row0 + 1) * OST + ct * 16 + r] = (unsigned short)(pk >> 16);
        }
    }
}

// ========================= gather-based aggregate ===========================
// 16 lanes/node, uint4 (8ch) per lane. (round-0 proven form)
__global__ __launch_bounds__(256) void k_agg128(
        const unsigned short* __restrict__ H, const int* __restrict__ rs,
        const int* __restrict__ re, const int* __restrict__ csr,
        const float* __restrict__ dinv, const float* __restrict__ b,
        unsigned short* __restrict__ outb, int N) {
    int lane = threadIdx.x & 15;
    int node = blockIdx.x * 16 + (threadIdx.x >> 4);
    if (node >= N) return;
    float dd  = dinv[node];
    int   beg = rs[node];
    int   end = re[node];
    uint4 hp  = ((const uint4*)(H + (size_t)node * 128))[lane];
    float4 bb0 = ((const float4*)b)[lane * 2];
    float4 bb1 = ((const float4*)b)[lane * 2 + 1];
    float sl = dd * dd;
    float a0 = fmaf(bflo(hp.x), sl, bb0.x), a1 = fmaf(bfhi(hp.x), sl, bb0.y);
    float a2 = fmaf(bflo(hp.y), sl, bb0.z), a3 = fmaf(bfhi(hp.y), sl, bb0.w);
    float a4 = fmaf(bflo(hp.z), sl, bb1.x), a5 = fmaf(bfhi(hp.z), sl, bb1.y);
    float a6 = fmaf(bflo(hp.w), sl, bb1.z), a7 = fmaf(bfhi(hp.w), sl, bb1.w);
    int j = beg;
    for (; j + 2 <= end; j += 2) {
        int s0 = csr[j], s1 = csr[j + 1];
        float n0 = dinv[s0] * dd, n1 = dinv[s1] * dd;
        uint4 v0 = ((const uint4*)(H + (size_t)s0 * 128))[lane];
        uint4 v1 = ((const uint4*)(H + (size_t)s1 * 128))[lane];
        a0 = fmaf(bflo(v0.x), n0, fmaf(bflo(v1.x), n1, a0));
        a1 = fmaf(bfhi(v0.x), n0, fmaf(bfhi(v1.x), n1, a1));
        a2 = fmaf(bflo(v0.y), n0, fmaf(bflo(v1.y), n1, a2));
        a3 = fmaf(bfhi(v0.y), n0, fmaf(bfhi(v1.y), n1, a3));
        a4 = fmaf(bflo(v0.z), n0, fmaf(bflo(v1.z), n1, a4));
        a5 = fmaf(bfhi(v0.z), n0, fmaf(bfhi(v1.z), n1, a5));
        a6 = fmaf(bflo(v0.w), n0, fmaf(bflo(v1.w), n1, a6));
        a7 = fmaf(bfhi(v0.w), n0, fmaf(bfhi(v1.w), n1, a7));
    }
    if (j < end) {
        int s0 = csr[j];
        float n0 = dinv[s0] * dd;
        uint4 v0 = ((const uint4*)(H + (size_t)s0 * 128))[lane];
        a0 = fmaf(bflo(v0.x), n0, a0); a1 = fmaf(bfhi(v0.x), n0, a1);
        a2 = fmaf(bflo(v0.y), n0, a2); a3 = fmaf(bfhi(v0.y), n0, a3);
        a4 = fmaf(bflo(v0.z), n0, a4); a5 = fmaf(bfhi(v0.z), n0, a5);
        a6 = fmaf(bflo(v0.w), n0, a6); a7 = fmaf(bfhi(v0.w), n0, a7);
    }
    uint4 o;
    o.x = f2bf2(a0, a1);
    o.y = f2bf2(a2, a3);
    o.z = f2bf2(a4, a5);
    o.w = f2bf2(a6, a7);
    ((uint4*)(outb + (size_t)node * 128))[lane] = o;
}

// 40-ch final from line-aligned stride-64 H (1 cache line per gathered row)
__global__ __launch_bounds__(256) void k_agg40(
        const unsigned short* __restrict__ H, const int* __restrict__ rs,
        const int* __restrict__ re, const int* __restrict__ csr,
        const float* __restrict__ dinv, const float* __restrict__ b,
        float* __restrict__ out, int N) {
    int lane = threadIdx.x & 15;
    int node = blockIdx.x * 16 + (threadIdx.x >> 4);
    if (node >= N || lane >= 10) return;
    float dd  = dinv[node];
    int   beg = rs[node];
    int   end = re[node];
    uint2 hp  = ((const uint2*)(H + (size_t)node * 64))[lane];
    float4 bb = ((const float4*)b)[lane];
    float  sl = dd * dd;
    float4 acc = make_float4(fmaf(bflo(hp.x), sl, bb.x), fmaf(bfhi(hp.x), sl, bb.y),
                             fmaf(bflo(hp.y), sl, bb.z), fmaf(bfhi(hp.y), sl, bb.w));
    int j = beg;
    for (; j + 2 <= end; j += 2) {
        int s0 = csr[j], s1 = csr[j + 1];
        float n0 = dinv[s0] * dd, n1 = dinv[s1] * dd;
        uint2 v0 = ((const uint2*)(H + (size_t)s0 * 64))[lane];
        uint2 v1 = ((const uint2*)(H + (size_t)s1 * 64))[lane];
        acc.x = fmaf(bflo(v0.x), n0, fmaf(bflo(v1.x), n1, acc.x));
        acc.y = fmaf(bfhi(v0.x), n0, fmaf(bfhi(v1.x), n1, acc.y));
        acc.z = fmaf(bflo(v0.y), n0, fmaf(bflo(v1.y), n1, acc.z));
        acc.w = fmaf(bfhi(v0.y), n0, fmaf(bfhi(v1.y), n1, acc.w));
    }
    if (j < end) {
        int s0 = csr[j];
        float n0 = dinv[s0] * dd;
        uint2 v0 = ((const uint2*)(H + (size_t)s0 * 64))[lane];
        acc.x = fmaf(bflo(v0.x), n0, acc.x);
        acc.y = fmaf(bfhi(v0.x), n0, acc.y);
        acc.z = fmaf(bflo(v0.y), n0, acc.z);
        acc.w = fmaf(bfhi(v0.y), n0, acc.w);
    }
    ((float4*)(out + (size_t)node * 40))[lane] = acc;
}

// =============================== BN stats ===================================
__global__ __launch_bounds__(256) void k_bnstats(
        const unsigned short* __restrict__ Bb, float* __restrict__ stats, int N) {
    __shared__ float red[2][16][128];
    const int t = threadIdx.x;
    const int lane16 = t & 15, grp = t >> 4;
    const int cbase = lane16 * 8;
    float s[8], q[8];
    #pragma unroll
    for (int k = 0; k < 8; ++k) { s[k] = 0.f; q[k] = 0.f; }

    const int step = gridDim.x * 16;
    for (int r = blockIdx.x * 16 + grp; r < N; r += 2 * step) {
        uint4 p0 = *((const uint4*)(Bb + (size_t)r * 128 + cbase));
        int r1 = r + step;
        if (r1 < N) {
            uint4 p1 = *((const uint4*)(Bb + (size_t)r1 * 128 + cbase));
            float v[8] = {bflo(p1.x), bfhi(p1.x), bflo(p1.y), bfhi(p1.y),
                          bflo(p1.z), bfhi(p1.z), bflo(p1.w), bfhi(p1.w)};
            #pragma unroll
            for (int k = 0; k < 8; ++k) { s[k] += v[k]; q[k] = fmaf(v[k], v[k], q[k]); }
        }
        float u[8] = {bflo(p0.x), bfhi(p0.x), bflo(p0.y), bfhi(p0.y),
                      bflo(p0.z), bfhi(p0.z), bflo(p0.w), bfhi(p0.w)};
        #pragma unroll
        for (int k = 0; k < 8; ++k) { s[k] += u[k]; q[k] = fmaf(u[k], u[k], q[k]); }
    }
    #pragma unroll
    for (int k = 0; k < 8; ++k) {
        red[0][grp][cbase + k] = s[k];
        red[1][grp][cbase + k] = q[k];
    }
    __syncthreads();
    if (t < 128) {
        float acc = 0.f;
        #pragma unroll
        for (int g = 0; g < 16; ++g) acc += red[0][g][t];
        unsafeAtomicAdd(&stats[t], acc);
    } else {
        int c = t - 128;
        float acc = 0.f;
        #pragma unroll
        for (int g = 0; g < 16; ++g) acc += red[1][g][c];
        unsafeAtomicAdd(&stats[128 + c], acc);
    }
}

// ================================ launch ====================================
extern "C" void kernel_launch(void* const* d_in, const int* in_sizes, int n_in,
                              void* d_out, int out_size, void* d_ws, size_t ws_size,
                              hipStream_t stream) {
    const float* x   = (const float*)d_in[0];
    const int*   ei  = (const int*)d_in[1];      // int64 in ref -> int32 from harness
    const float* W0  = (const float*)d_in[2];
    const float* b0  = (const float*)d_in[3];
    const float* g0  = (const float*)d_in[4];
    const float* be0 = (const float*)d_in[5];
    const float* W1  = (const float*)d_in[6];
    const float* b1  = (const float*)d_in[7];
    const float* g1  = (const float*)d_in[8];
    const float* be1 = (const float*)d_in[9];
    const float* W2  = (const float*)d_in[10];
    const float* b2  = (const float*)d_in[11];
    float* out = (float*)d_out;

    const int N  = in_sizes[0] / 128;   // 170000
    const int E  = in_sizes[1] / 2;     // 1200000
    const int NB = (N + 255) >> 8;      // 665 buckets
    const int EB = (E + 8191) / 8192;   // 147 edge-chunk blocks

    // ws layout (4B units)
    float* ws   = (float*)d_ws;
    size_t Npad = ((size_t)N + 511) & ~(size_t)511;
    size_t BCAP = (size_t)NB * CAP;
    float* dinv = ws;
    int*   rs   = (int*)(ws + Npad);
    int*   re   = rs + Npad;
    int*   csr  = re + Npad;                            // BCAP
    unsigned int* ebuf = (unsigned int*)(csr + BCAP);   // BCAP
    int*   bcur = (int*)(ebuf + BCAP);                  // 1024
    float* stats0 = (float*)(bcur + 1024);              // 256
    float* stats1 = stats0 + 256;                       // 256
    unsigned short* Wf = (unsigned short*)(stats1 + 256); // 3*16384 ushort
    unsigned short* Hb = Wf + 3 * 16384;                // Npad*128 bf16
    unsigned short* Bb = Hb + Npad * 128;               // Npad*128 bf16

    // ---- prep (init folded) + CSR build: 3 dispatches ----
    k_prepW3  <<<24, 256, 0, stream>>>(W0, W1, W2, Wf, bcur, stats0, NB);
    k_bscatter<<<EB, 256, 0, stream>>>(ei, bcur, ebuf, E, NB);
    k_bfinal  <<<NB, 256, 0, stream>>>(ebuf, bcur, csr, rs, re, dinv, N);

    int gemm_grid = (N + 63) / 64;
    int agg_grid  = (N + 15) / 16;

    // ---- layer 0 ----
    k_gemm_mfma<8, 128><<<gemm_grid, 256, 0, stream>>>(x, 1, Wf, Hb, N,
                                                       nullptr, nullptr, nullptr);
    k_agg128<<<agg_grid, 256, 0, stream>>>(Hb, rs, re, csr, dinv, b0, Bb, N);
    k_bnstats<<<512, 256, 0, stream>>>(Bb, stats0, N);

    // ---- layer 1 (BN0+ReLU fused into GEMM staging, LDS-precomputed) ----
    k_gemm_mfma<8, 128><<<gemm_grid, 256, 0, stream>>>(Bb, 0, Wf + 16384, Hb, N,
                                                       stats0, g0, be0);
    k_agg128<<<agg_grid, 256, 0, stream>>>(Hb, rs, re, csr, dinv, b1, Bb, N);
    k_bnstats<<<512, 256, 0, stream>>>(Bb, stats1, N);

    // ---- layer 2 (BN1+ReLU fused) -> line-aligned 64-stride H -> 40-ch out ----
    k_gemm_mfma<3, 64><<<gemm_grid, 256, 0, stream>>>(Bb, 0, Wf + 2 * 16384, Hb, N,
                                                      stats1, g1, be1);
    k_agg40<<<agg_grid, 256, 0, stream>>>(Hb, rs, re, csr, dinv, b2, out, N);
}